// Round 1
// baseline (431.138 us; speedup 1.0000x reference)
//
#include <hip/hip_runtime.h>
#include <stdint.h>

#define K_DIM 4096
#define M_TOK 8192
#define N_OUT 4096

typedef int v4i __attribute__((ext_vector_type(4)));

// ---- workspace layout (bytes) ----
// q   : int8 [8192][4096]   @ 0          (33554432)
// tw  : int8 [4096][4096]   @ 33554432   (16777216)
// rs  : float[8192]         @ 50331648   (32768)
// acc : double              @ 50364416   (8)

__device__ __forceinline__ void gload_lds16(const void* g, void* l) {
    auto gp = reinterpret_cast<const __attribute__((address_space(1))) uint32_t*>(
        reinterpret_cast<uintptr_t>(g));
    auto lp = reinterpret_cast<__attribute__((address_space(3))) uint32_t*>(
        reinterpret_cast<uintptr_t>(l));
    __builtin_amdgcn_global_load_lds(gp, lp, 16, 0, 0);
}

__global__ void init_acc(double* acc) { *acc = 0.0; }

// --- per-token activation quantization: q = clip(round(x*s),-128,127), rs = 1/s ---
__global__ __launch_bounds__(256) void quant_act(const float* __restrict__ x,
                                                 int8_t* __restrict__ q,
                                                 float* __restrict__ rs) {
    const int token = blockIdx.x;
    const int t = threadIdx.x;
    const float4* x4 = (const float4*)(x + (size_t)token * K_DIM);
    float4 v[4];
    float m = 0.0f;
#pragma unroll
    for (int r = 0; r < 4; ++r) {
        v[r] = x4[t + 256 * r];
        m = fmaxf(m, fmaxf(fmaxf(fabsf(v[r].x), fabsf(v[r].y)),
                           fmaxf(fabsf(v[r].z), fabsf(v[r].w))));
    }
#pragma unroll
    for (int off = 32; off; off >>= 1) m = fmaxf(m, __shfl_down(m, off, 64));
    __shared__ float wmax[4];
    __shared__ float smax;
    if ((t & 63) == 0) wmax[t >> 6] = m;
    __syncthreads();
    if (t == 0) smax = fmaxf(fmaxf(wmax[0], wmax[1]), fmaxf(wmax[2], wmax[3]));
    __syncthreads();
    const float s = 127.0f / fmaxf(smax, 1e-5f);
    char4* q4 = (char4*)(q + (size_t)token * K_DIM);
#pragma unroll
    for (int r = 0; r < 4; ++r) {
        float4 f = v[r];
        char4 c;
        c.x = (signed char)fminf(fmaxf(rintf(f.x * s), -128.0f), 127.0f);
        c.y = (signed char)fminf(fmaxf(rintf(f.y * s), -128.0f), 127.0f);
        c.z = (signed char)fminf(fmaxf(rintf(f.z * s), -128.0f), 127.0f);
        c.w = (signed char)fminf(fmaxf(rintf(f.w * s), -128.0f), 127.0f);
        q4[t + 256 * r] = c;
    }
    if (t == 0) rs[token] = 1.0f / s;
}

// --- sum |w| into fp64 accumulator ---
__global__ __launch_bounds__(256) void wabs_sum(const float* __restrict__ w,
                                                double* __restrict__ acc) {
    const size_t n4 = (size_t)N_OUT * K_DIM / 4;
    const size_t stride = (size_t)gridDim.x * 256;
    const float4* w4 = (const float4*)w;
    float sum = 0.0f;
    for (size_t j = (size_t)blockIdx.x * 256 + threadIdx.x; j < n4; j += stride) {
        float4 f = w4[j];
        sum += fabsf(f.x) + fabsf(f.y) + fabsf(f.z) + fabsf(f.w);
    }
    double d = (double)sum;
#pragma unroll
    for (int off = 32; off; off >>= 1) d += __shfl_down(d, off, 64);
    __shared__ double wsum[4];
    const int t = threadIdx.x;
    if ((t & 63) == 0) wsum[t >> 6] = d;
    __syncthreads();
    if (t == 0) atomicAdd(acc, wsum[0] + wsum[1] + wsum[2] + wsum[3]);
}

// --- ternarize: tw = clip(round(w*scale_w),-1,1), scale_w = 1/clip(mean|w|,eps) ---
__global__ __launch_bounds__(256) void ternarize(const float* __restrict__ w,
                                                 int8_t* __restrict__ tw,
                                                 const double* __restrict__ acc) {
    const double mean = *acc * (1.0 / ((double)N_OUT * (double)K_DIM));
    const float sw = 1.0f / fmaxf((float)mean, 1e-5f);
    const size_t i = (size_t)blockIdx.x * 256 + threadIdx.x;
    const float4* w4 = (const float4*)w;
    char4* t4 = (char4*)tw;
    float4 f = w4[i];
    char4 c;
    c.x = (signed char)fminf(fmaxf(rintf(f.x * sw), -1.0f), 1.0f);
    c.y = (signed char)fminf(fmaxf(rintf(f.y * sw), -1.0f), 1.0f);
    c.z = (signed char)fminf(fmaxf(rintf(f.z * sw), -1.0f), 1.0f);
    c.w = (signed char)fminf(fmaxf(rintf(f.w * sw), -1.0f), 1.0f);
    t4[i] = c;
}

// --- i8 GEMM: out[m,n] = (sum_k q[m,k]*tw[n,k]) * rs[m] * clip(mean|w|,eps) ---
// 128x128 tile, BK=64, 4 waves (2x2), each wave 4x4 of 16x16x64 MFMA tiles.
__global__ __launch_bounds__(256) void gemm_i8(const int8_t* __restrict__ A,
                                               const int8_t* __restrict__ B,
                                               const float* __restrict__ rs,
                                               const double* __restrict__ acc,
                                               float* __restrict__ out) {
    const int bm = blockIdx.y * 128;
    const int bn = blockIdx.x * 128;
    __shared__ int8_t As[128 * 64];
    __shared__ int8_t Bs[128 * 64];
    const int t = threadIdx.x;
    const int lane = t & 63;
    const int wave = t >> 6;
    const int wm = (wave >> 1) * 64;
    const int wn = (wave & 1) * 64;

    v4i accv[4][4] = {};

    // staging: thread t loads 16B: row t>>2 (0..63), byte col (t&3)*16; twice (row, row+64)
    const int srow = t >> 2;
    const int scol = (t & 3) * 16;
    const int8_t* Ag = A + (size_t)(bm + srow) * K_DIM + scol;
    const int8_t* Bg = B + (size_t)(bn + srow) * K_DIM + scol;
    int8_t* lA0 = As + t * 16;
    int8_t* lA1 = As + 4096 + t * 16;
    int8_t* lB0 = Bs + t * 16;
    int8_t* lB1 = Bs + 4096 + t * 16;

    const int kb = (lane >> 4) * 16;        // K sub-offset within BK=64
    const int fr = lane & 15;               // fragment row (m or n)

    for (int k0 = 0; k0 < K_DIM; k0 += 64) {
        gload_lds16(Ag + k0, lA0);
        gload_lds16(Ag + (size_t)64 * K_DIM + k0, lA1);
        gload_lds16(Bg + k0, lB0);
        gload_lds16(Bg + (size_t)64 * K_DIM + k0, lB1);
        __syncthreads();

        v4i af[4], bf[4];
#pragma unroll
        for (int i = 0; i < 4; ++i)
            af[i] = *(const v4i*)(As + (wm + i * 16 + fr) * 64 + kb);
#pragma unroll
        for (int j = 0; j < 4; ++j)
            bf[j] = *(const v4i*)(Bs + (wn + j * 16 + fr) * 64 + kb);
#pragma unroll
        for (int i = 0; i < 4; ++i)
#pragma unroll
            for (int j = 0; j < 4; ++j)
                accv[i][j] = __builtin_amdgcn_mfma_i32_16x16x64_i8(af[i], bf[j], accv[i][j], 0, 0, 0);
        __syncthreads();
    }

    // epilogue: C/D layout col=lane&15, row=(lane>>4)*4+reg
    const double mean = *acc * (1.0 / ((double)N_OUT * (double)K_DIM));
    const float wmean = fmaxf((float)mean, 1e-5f);  // == 1/scale_w
    const int crow0 = (lane >> 4) * 4;
    const int ccol = lane & 15;
#pragma unroll
    for (int i = 0; i < 4; ++i) {
        const int rbase = bm + wm + i * 16 + crow0;
#pragma unroll
        for (int reg = 0; reg < 4; ++reg) {
            const int r = rbase + reg;
            const float scale = rs[r] * wmean;
            float* orow = out + (size_t)r * N_OUT + bn + wn + ccol;
#pragma unroll
            for (int j = 0; j < 4; ++j)
                orow[j * 16] = (float)accv[i][j][reg] * scale;
        }
    }
}

extern "C" void kernel_launch(void* const* d_in, const int* in_sizes, int n_in,
                              void* d_out, int out_size, void* d_ws, size_t ws_size,
                              hipStream_t stream) {
    const float* x = (const float*)d_in[0];
    const float* w = (const float*)d_in[1];
    float* out = (float*)d_out;
    char* ws = (char*)d_ws;
    int8_t* q = (int8_t*)ws;
    int8_t* tw = (int8_t*)(ws + 33554432);
    float* rs = (float*)(ws + 50331648);
    double* acc = (double*)(ws + 50364416);

    hipLaunchKernelGGL(init_acc, dim3(1), dim3(1), 0, stream, acc);
    hipLaunchKernelGGL(quant_act, dim3(M_TOK), dim3(256), 0, stream, x, q, rs);
    hipLaunchKernelGGL(wabs_sum, dim3(1024), dim3(256), 0, stream, w, acc);
    hipLaunchKernelGGL(ternarize, dim3((N_OUT * (size_t)K_DIM / 4) / 256), dim3(256), 0, stream, w, tw, acc);
    hipLaunchKernelGGL(gemm_i8, dim3(N_OUT / 128, M_TOK / 128), dim3(256), 0, stream, q, tw, rs, acc, out);
}